// Round 7
// baseline (450.189 us; speedup 1.0000x reference)
//
#include <hip/hip_runtime.h>

// Problem constants
#define NP 2048          // B*H1*W1 points
#define CD 768           // channels
#define NSPLIT 24        // channel splits for d2 partials (32 ch each)
#define NJOBS 528        // 136 XX-tri + 136 YY-tri + 256 XY tiles
#define MMD_GAMMA 0.00065f
#define AGENT __HIP_MEMORY_SCOPE_AGENT

typedef short bf16frag __attribute__((ext_vector_type(8)));
typedef float f32x4 __attribute__((ext_vector_type(4)));

#define GLD16(g, l)  __builtin_amdgcn_global_load_lds(                      \
    (const __attribute__((address_space(1))) void*)(g),                     \
    (__attribute__((address_space(3))) void*)(l), 16, 0, 0)

static __device__ inline unsigned short f2bf(float v) {
    union { float f; unsigned u; } a; a.f = v;
    unsigned r = a.u + 0x7fffu + ((a.u >> 16) & 1u);
    return (unsigned short)(r >> 16);
}

// ---------------------------------------------------------------------------
// Fused prep + embedded argmax (dataflow sync, no grid barrier, no spin):
//   blocks 0..1535  = d2 f64 partials (R5 mapping, bit-identical order).
//     d2p written with agent-scope atomic stores (cross-XCD coherent);
//     after threadfence, tid0 bumps cnt[bh]; the 24th (last) unit for a
//     given bh runs the argmax inline with agent-scope atomic loads,
//     summation order byte-identical to R5's k_argmax -> identical bidx.
//   blocks 1536..2303 = x transpose + bf16 pack + a2 partials (unchanged).
__global__ __launch_bounds__(256, 6)
void k_prep_am(const float* __restrict__ x, const float* __restrict__ y,
               double* __restrict__ d2p, unsigned short* __restrict__ Xhi,
               float* __restrict__ a2f, unsigned int* __restrict__ cnt,
               int* __restrict__ bidx) {
    __shared__ __attribute__((aligned(16))) unsigned char smem[9472];
    double* redd  = (double*)smem;                    // 8 KB  [8][32][4] (d2)
    double (*s2)[32] = (double(*)[32])smem;           // 4 KB overlay (argmax)
    float*  tile  = (float*)smem;                     // 8.4 KB [64][33] (transpose)
    float*  sqred = (float*)(smem + 8448);            // 1 KB  [8][32] (transpose)
    __shared__ int sLast;

    int bid = blockIdx.x;
    int tid = threadIdx.x;

    if (bid < 1536) {
        // ---- d2 partial branch (math/order identical to R5) ----
        int cs = bid >> 6;               // 0..23 (32 channels each)
        int r6 = bid & 63;               // bh = b*32 + h1
        int b = r6 >> 5, h1 = r6 & 31;
        int cg = tid >> 5, w1 = tid & 31;
        int cbase = cs * 32;

        double acc[4][4] = {};

        #pragma unroll
        for (int kk = 0; kk < 4; ++kk) {
            int c = cbase + 8 * kk + cg;             // ascending per thread
            const float* yrow =
                y + ((size_t)(b * 768 + c) * 128 + 4 * h1) * 128 + 4 * w1;
            float4 yv0 = *(const float4*)(yrow);
            float4 yv1 = *(const float4*)(yrow + 128);
            float4 yv2 = *(const float4*)(yrow + 256);
            float4 yv3 = *(const float4*)(yrow + 384);
            float xv = x[(size_t)(b * 768 + c) * 1024 + h1 * 32 + w1];
            double xd = (double)xv;
            double d;
            d = xd - (double)yv0.x; acc[0][0] += d * d;
            d = xd - (double)yv0.y; acc[0][1] += d * d;
            d = xd - (double)yv0.z; acc[0][2] += d * d;
            d = xd - (double)yv0.w; acc[0][3] += d * d;
            d = xd - (double)yv1.x; acc[1][0] += d * d;
            d = xd - (double)yv1.y; acc[1][1] += d * d;
            d = xd - (double)yv1.z; acc[1][2] += d * d;
            d = xd - (double)yv1.w; acc[1][3] += d * d;
            d = xd - (double)yv2.x; acc[2][0] += d * d;
            d = xd - (double)yv2.y; acc[2][1] += d * d;
            d = xd - (double)yv2.z; acc[2][2] += d * d;
            d = xd - (double)yv2.w; acc[2][3] += d * d;
            d = xd - (double)yv3.x; acc[3][0] += d * d;
            d = xd - (double)yv3.y; acc[3][1] += d * d;
            d = xd - (double)yv3.z; acc[3][2] += d * d;
            d = xd - (double)yv3.w; acc[3][3] += d * d;
        }
        int n0 = b * 1024 + h1 * 32;
        #pragma unroll 1
        for (int i = 0; i < 4; ++i) {
            __syncthreads();                         // guards round reuse
            int base = (cg * 32 + w1) * 4;
            redd[base + 0] = acc[i][0]; redd[base + 1] = acc[i][1];
            redd[base + 2] = acc[i][2]; redd[base + 3] = acc[i][3];
            __syncthreads();
            if (tid < 128) {
                int w = tid & 31, jj = tid >> 5;
                double s = 0.0;
                #pragma unroll
                for (int g = 0; g < 8; ++g) s += redd[(g * 32 + w) * 4 + jj];
                // agent-scope store: coherent for the in-kernel finalizer
                __hip_atomic_store(&d2p[((size_t)(cs * 16) + i * 4 + jj) * NP + n0 + w],
                                   s, __ATOMIC_RELAXED, AGENT);
            }
        }
        // ---- last-arriver argmax (no spin: 24th unit does the work) ----
        __syncthreads();
        __threadfence();                             // release d2p stores
        if (tid == 0) {
            unsigned int old = atomicAdd(&cnt[r6], 1u);
            sLast = (old == NSPLIT - 1);
        }
        __syncthreads();
        if (sLast) {
            __threadfence();                         // acquire side
            int k8 = tid >> 5, nl = tid & 31;
            #pragma unroll
            for (int kk = 0; kk < 2; ++kk) {
                int k = k8 + kk * 8;
                double s = 0.0;
                #pragma unroll
                for (int c = 0; c < NSPLIT; ++c)     // c ascending: R5 order
                    s += __hip_atomic_load(&d2p[((size_t)c * 16 + k) * NP + n0 + nl],
                                           __ATOMIC_RELAXED, AGENT);
                s2[k][nl] = s;
            }
            __syncthreads();
            if (tid < 32) {
                double best = s2[0][tid]; int bi = 0;
                #pragma unroll
                for (int k = 1; k < 16; ++k) {
                    double v = s2[k][tid];
                    if (v > best) { best = v; bi = k; }
                }
                bidx[n0 + tid] = bi;                 // read by next kernel
            }
        }
    } else {
        // ---- transpose + pack branch (unchanged) ----
        int id = bid - 1536;
        int bx = id & 63;
        int c0 = (id >> 6) * 64;
        int b = bx >> 5, h1 = bx & 31;
        const float* src = x + (size_t)(b * 768 + c0) * 1024 + h1 * 32;
        #pragma unroll
        for (int p = 0; p < 8; ++p) {
            int cl = p * 8 + (tid >> 5);
            int w1 = tid & 31;
            tile[cl * 33 + w1] = src[(size_t)cl * 1024 + w1];
        }
        __syncthreads();
        int n0 = bx * 32;
        #pragma unroll
        for (int p = 0; p < 8; ++p) {
            int w1 = p * 4 + (tid >> 6);
            int c  = tid & 63;
            float v = tile[c * 33 + w1];
            size_t o = (size_t)(n0 + w1) * CD + c0 + c;
            Xhi[o] = f2bf(v);
        }
        {
            int w1 = tid & 31, cseg = tid >> 5;
            float s = 0.f;
            #pragma unroll
            for (int u = 0; u < 8; ++u) {
                float v = tile[(cseg * 8 + u) * 33 + w1];
                s += v * v;
            }
            sqred[cseg * 32 + w1] = s;
        }
        __syncthreads();
        if (tid < 32) {
            float s = 0.f;
            #pragma unroll
            for (int g = 0; g < 8; ++g) s += sqred[g * 32 + tid];
            atomicAdd(&a2f[n0 + tid], s);
        }
    }
}

// ---------------------------------------------------------------------------
// Gather + bf16 pack + b2 partial norms (R5 verbatim; y read from L3;
// bidx crosses a kernel boundary -> dispatch-boundary coherence).
__global__ __launch_bounds__(256, 4)
void k_gather_pack_y(const float* __restrict__ y, const int* __restrict__ bidx,
                     unsigned short* __restrict__ Yhi,
                     float* __restrict__ b2f) {
    __shared__ float ytile[8][520];
    __shared__ int sOff[32];
    __shared__ float sqred[32][8];
    int bh = blockIdx.x;                // b*32 + h1
    int cs = blockIdx.y;                // 0..11, 64 channels each
    int b = bh >> 5, h1 = bh & 31;
    int tid = threadIdx.x;
    if (tid < 32) {
        int bi = bidx[b * 1024 + h1 * 32 + tid];
        sOff[tid] = (bi >> 2) * 128 + 4 * tid + (bi & 3);
    }
    __syncthreads();
    int c_loc = tid & 7, n_loc = tid >> 3;
    int ch_s = tid >> 5, part = tid & 31;
    int off = sOff[n_loc];
    int n = b * 1024 + h1 * 32 + n_loc;
    float sq = 0.f;
    for (int kt = 0; kt < 8; ++kt) {
        int c0 = cs * 64 + kt * 8;
        __syncthreads();
        const float* src = y + ((size_t)(b * 768 + c0 + ch_s) * 128 + 4 * h1) * 128;
        #pragma unroll
        for (int u = 0; u < 4; ++u)
            *(float4*)&ytile[ch_s][u * 128 + part * 4] = *(const float4*)(src + u * 128 + part * 4);
        __syncthreads();
        float v = ytile[c_loc][off];
        size_t o = (size_t)n * CD + c0 + c_loc;
        Yhi[o] = f2bf(v);
        sq += v * v;
    }
    sqred[n_loc][c_loc] = sq;
    __syncthreads();
    if (tid < 32) {
        float s = 0.f;
        #pragma unroll
        for (int g = 0; g < 8; ++g) s += sqred[tid][g];
        atomicAdd(&b2f[b * 1024 + h1 * 32 + tid], s);
    }
}

// ---------------------------------------------------------------------------
// MFMA Gram + exp-sum, 1-term (Gram = a_hi . b_hi), K=768 as 12 windows of
// K=64; XOR-(r&7) swizzle on 64-short rows; bijective XCD block swizzle.
__global__ __launch_bounds__(256, 3)
void k_mmd_mfma(const unsigned short* __restrict__ Xhi,
                const unsigned short* __restrict__ Yhi,
                const float* __restrict__ a2, const float* __restrict__ b2,
                double* __restrict__ accg, unsigned int* __restrict__ done,
                float* __restrict__ out) {
    __shared__ unsigned short As[128 * 64];   // 16 KB
    __shared__ unsigned short Bs[128 * 64];   // 16 KB
    __shared__ float red[256];

    int bid0 = blockIdx.x;
    int id = (bid0 & 7) * 66 + (bid0 >> 3);   // XCD swizzle, bijective (528=8*66)
    int z, bx, by;
    double w = 1.0;
    if (id < 272) {
        z = (id < 136) ? 0 : 1;
        if (id >= 136) id -= 136;
        int r = 0;
        while (id >= 16 - r) { id -= 16 - r; ++r; }
        by = r; bx = r + id;
        if (bx != by) w = 2.0;
    } else {
        z = 2; id -= 272;
        bx = id & 15; by = id >> 4;
    }
    const unsigned short* AH = (z == 1) ? Yhi : Xhi;
    const unsigned short* BH = (z == 0) ? Xhi : Yhi;
    const float* na = (z == 1) ? b2 : a2;
    const float* nb = (z == 0) ? a2 : b2;
    int i0 = by * 128, j0 = bx * 128;

    int tid = threadIdx.x;
    int lane = tid & 63;
    int wv = tid >> 6;
    int wr = wv >> 1, wc = wv & 1;
    int m = lane & 15, q = lane >> 4;
    int lrow = lane >> 3, lchunk = lane & 7;   // staging: 8 rows x 8 chunks/wave

    f32x4 acc[4][4] = {};

    for (int wnd = 0; wnd < 12; ++wnd) {
        int c0 = wnd * 64;
        __syncthreads();
        #pragma unroll
        for (int s = 0; s < 4; ++s) {
            int r0 = s * 32 + wv * 8;
            int r  = r0 + lrow;
            int cg = lchunk ^ (r & 7);
            GLD16(AH + (size_t)(i0 + r) * CD + c0 + cg * 8, &As[r0 * 64]);
        }
        #pragma unroll
        for (int s = 0; s < 4; ++s) {
            int r0 = s * 32 + wv * 8;
            int r  = r0 + lrow;
            int cg = lchunk ^ (r & 7);
            GLD16(BH + (size_t)(j0 + r) * CD + c0 + cg * 8, &Bs[r0 * 64]);
        }
        __syncthreads();
        #pragma unroll
        for (int kh = 0; kh < 2; ++kh) {      // two K=32 halves of the window
            bf16frag af[4], bg[4];
            #pragma unroll
            for (int t = 0; t < 4; ++t) {
                int ra = wr * 64 + t * 16 + m;
                af[t] = *(const bf16frag*)&As[ra * 64 + ((kh * 4 + q) ^ (ra & 7)) * 8];
            }
            #pragma unroll
            for (int t = 0; t < 4; ++t) {
                int rb = wc * 64 + t * 16 + m;
                bg[t] = *(const bf16frag*)&Bs[rb * 64 + ((kh * 4 + q) ^ (rb & 7)) * 8];
            }
            #pragma unroll
            for (int ti = 0; ti < 4; ++ti)
                #pragma unroll
                for (int tj = 0; tj < 4; ++tj)
                    acc[ti][tj] = __builtin_amdgcn_mfma_f32_16x16x32_bf16(
                        af[ti], bg[tj], acc[ti][tj], 0, 0, 0);
        }
    }

    float s = 0.0f;
    #pragma unroll
    for (int ti = 0; ti < 4; ++ti) {
        #pragma unroll
        for (int r = 0; r < 4; ++r) {
            int i = i0 + wr * 64 + ti * 16 + q * 4 + r;
            float ai = na[i];
            #pragma unroll
            for (int tj = 0; tj < 4; ++tj) {
                int j = j0 + wc * 64 + tj * 16 + m;
                float d = ai + nb[j] - 2.0f * acc[ti][tj][r];
                d = fmaxf(d, 0.0f);
                s += expf(-MMD_GAMMA * d);
            }
        }
    }
    red[tid] = s;
    __syncthreads();
    for (int st = 128; st > 0; st >>= 1) {
        if (tid < st) red[tid] += red[tid + st];
        __syncthreads();
    }
    if (tid == 0) {
        atomicAdd(&accg[z], w * (double)red[0]);
        __threadfence();                           // accg visible before done++
        unsigned int d = atomicAdd(done, 1u);
        if (d == (unsigned int)(NJOBS - 1)) {      // last block finalizes
            double kxx = atomicAdd(&accg[0], 0.0); // atomic-RMW read: coherent
            double kyy = atomicAdd(&accg[1], 0.0);
            double kxy = atomicAdd(&accg[2], 0.0);
            const double inv = 1.0 / ((double)NP * (double)NP);
            out[0] = (float)((kxx + kyy - 2.0 * kxy) * inv);
        }
    }
}

extern "C" void kernel_launch(void* const* d_in, const int* in_sizes, int n_in,
                              void* d_out, int out_size, void* d_ws, size_t ws_size,
                              hipStream_t stream) {
    const float* x = (const float*)d_in[0];
    const float* y = (const float*)d_in[1];
    float* out = (float*)d_out;

    char* ws = (char*)d_ws;
    double*       acc  = (double*)ws;                 // [0,24)
    unsigned int* done = (unsigned int*)(ws + 64);    // 4B
    unsigned int* cnt  = (unsigned int*)(ws + 128);   // 64 x 4B (bh counters)
    float*  b2f  = (float*)(ws + 4096);               // 8KB
    float*  a2f  = (float*)(ws + 12288);              // 8KB
    int*    bidx = (int*)(ws + 20480);                // 8KB (fully overwritten)
    double* d2p  = (double*)(ws + 32768);             // 6.29MB -> ends 6324224
    unsigned short* Xhi = (unsigned short*)(ws + 6324224);   // 3.0MB
    unsigned short* Yhi = (unsigned short*)(ws + 9469952);   // 3.0MB

    hipMemsetAsync(ws, 0, 20480, stream);             // acc + done + cnt + b2f + a2f
    k_prep_am<<<2304, 256, 0, stream>>>(x, y, d2p, Xhi, a2f, cnt, bidx);
    k_gather_pack_y<<<dim3(64, 12), 256, 0, stream>>>(y, bidx, Yhi, b2f);
    k_mmd_mfma<<<NJOBS, 256, 0, stream>>>(Xhi, Yhi, a2f, b2f, acc, done, out);
}

// Round 8
// 223.741 us; speedup vs baseline: 2.0121x; 2.0121x over previous
//
#include <hip/hip_runtime.h>

// Problem constants
#define NP 2048          // B*H1*W1 points
#define CD 768           // channels
#define NSPLIT 24        // channel splits for d2 partials (32 ch each)
#define NJOBS 528        // 136 XX-tri + 136 YY-tri + 256 XY tiles
#define MMD_GAMMA 0.00065f

typedef short bf16frag __attribute__((ext_vector_type(8)));
typedef float f32x4 __attribute__((ext_vector_type(4)));

#define GLD16(g, l)  __builtin_amdgcn_global_load_lds(                      \
    (const __attribute__((address_space(1))) void*)(g),                     \
    (__attribute__((address_space(3))) void*)(l), 16, 0, 0)

static __device__ inline unsigned short f2bf(float v) {
    union { float f; unsigned u; } a; a.f = v;
    unsigned r = a.u + 0x7fffu + ((a.u >> 16) & 1u);
    return (unsigned short)(r >> 16);
}

// ---------------------------------------------------------------------------
// Fused prep (R5 verbatim — fastest measured d2 structure, plain stores):
//   blocks 0..1535  = d2 f64 partials, contiguous 2KB y reads, d2p [row][n]
//   blocks 1536..2303 = x transpose + bf16 pack + a2 partials.
__global__ __launch_bounds__(256, 6)
void k_prep(const float* __restrict__ x, const float* __restrict__ y,
            double* __restrict__ d2p,
            unsigned short* __restrict__ Xhi,
            float* __restrict__ a2f) {
    __shared__ __attribute__((aligned(16))) unsigned char smem[9472];
    double* redd  = (double*)smem;                    // 8 KB  [8][32][4]
    float*  tile  = (float*)smem;                     // 8.4 KB [64][33]
    float*  sqred = (float*)(smem + 8448);            // 1 KB  [8][32]

    int bid = blockIdx.x;
    int tid = threadIdx.x;

    if (bid < 1536) {
        // ---- d2 partial branch ----
        int cs = bid >> 6;               // 0..23 (32 channels each)
        int r6 = bid & 63;
        int b = r6 >> 5, h1 = r6 & 31;
        int cg = tid >> 5, w1 = tid & 31;
        int cbase = cs * 32;

        double acc[4][4] = {};

        #pragma unroll
        for (int kk = 0; kk < 4; ++kk) {
            int c = cbase + 8 * kk + cg;             // ascending per thread
            const float* yrow =
                y + ((size_t)(b * 768 + c) * 128 + 4 * h1) * 128 + 4 * w1;
            float4 yv0 = *(const float4*)(yrow);
            float4 yv1 = *(const float4*)(yrow + 128);
            float4 yv2 = *(const float4*)(yrow + 256);
            float4 yv3 = *(const float4*)(yrow + 384);
            float xv = x[(size_t)(b * 768 + c) * 1024 + h1 * 32 + w1];
            double xd = (double)xv;
            double d;
            d = xd - (double)yv0.x; acc[0][0] += d * d;
            d = xd - (double)yv0.y; acc[0][1] += d * d;
            d = xd - (double)yv0.z; acc[0][2] += d * d;
            d = xd - (double)yv0.w; acc[0][3] += d * d;
            d = xd - (double)yv1.x; acc[1][0] += d * d;
            d = xd - (double)yv1.y; acc[1][1] += d * d;
            d = xd - (double)yv1.z; acc[1][2] += d * d;
            d = xd - (double)yv1.w; acc[1][3] += d * d;
            d = xd - (double)yv2.x; acc[2][0] += d * d;
            d = xd - (double)yv2.y; acc[2][1] += d * d;
            d = xd - (double)yv2.z; acc[2][2] += d * d;
            d = xd - (double)yv2.w; acc[2][3] += d * d;
            d = xd - (double)yv3.x; acc[3][0] += d * d;
            d = xd - (double)yv3.y; acc[3][1] += d * d;
            d = xd - (double)yv3.z; acc[3][2] += d * d;
            d = xd - (double)yv3.w; acc[3][3] += d * d;
        }
        int n0 = b * 1024 + h1 * 32;
        #pragma unroll 1
        for (int i = 0; i < 4; ++i) {
            __syncthreads();                         // guards round reuse
            int base = (cg * 32 + w1) * 4;
            redd[base + 0] = acc[i][0]; redd[base + 1] = acc[i][1];
            redd[base + 2] = acc[i][2]; redd[base + 3] = acc[i][3];
            __syncthreads();
            if (tid < 128) {
                int w = tid & 31, jj = tid >> 5;
                double s = 0.0;
                #pragma unroll
                for (int g = 0; g < 8; ++g) s += redd[(g * 32 + w) * 4 + jj];
                d2p[((size_t)(cs * 16) + i * 4 + jj) * NP + n0 + w] = s;
            }
        }
    } else {
        // ---- transpose + pack branch (unchanged) ----
        int id = bid - 1536;
        int bx = id & 63;
        int c0 = (id >> 6) * 64;
        int b = bx >> 5, h1 = bx & 31;
        const float* src = x + (size_t)(b * 768 + c0) * 1024 + h1 * 32;
        #pragma unroll
        for (int p = 0; p < 8; ++p) {
            int cl = p * 8 + (tid >> 5);
            int w1 = tid & 31;
            tile[cl * 33 + w1] = src[(size_t)cl * 1024 + w1];
        }
        __syncthreads();
        int n0 = bx * 32;
        #pragma unroll
        for (int p = 0; p < 8; ++p) {
            int w1 = p * 4 + (tid >> 6);
            int c  = tid & 63;
            float v = tile[c * 33 + w1];
            size_t o = (size_t)(n0 + w1) * CD + c0 + c;
            Xhi[o] = f2bf(v);
        }
        {
            int w1 = tid & 31, cseg = tid >> 5;
            float s = 0.f;
            #pragma unroll
            for (int u = 0; u < 8; ++u) {
                float v = tile[(cseg * 8 + u) * 33 + w1];
                s += v * v;
            }
            sqred[cseg * 32 + w1] = s;
        }
        __syncthreads();
        if (tid < 32) {
            float s = 0.f;
            #pragma unroll
            for (int g = 0; g < 8; ++g) s += sqred[g * 32 + tid];
            atomicAdd(&a2f[n0 + tid], s);
        }
    }
}

// ---------------------------------------------------------------------------
// Gather + bf16 pack + b2, with the argmax EMBEDDED at block start (R5's
// k_argmax logic verbatim -> bit-identical winners; the 12 cs-duplicates are
// L2-hot and cheap). Saves one kernel launch + drain boundary + bidx trip.
// LDS: s2[16][32] (4KB) overlays the ytile region (dead at that point).
__global__ __launch_bounds__(256, 4)
void k_gather_pack_y(const float* __restrict__ y, const double* __restrict__ d2p,
                     unsigned short* __restrict__ Yhi,
                     float* __restrict__ b2f) {
    __shared__ __attribute__((aligned(16))) unsigned char smem[17920];
    float (*ytile)[520] = (float(*)[520])smem;        // 16.6 KB
    double (*s2)[32]    = (double(*)[32])smem;        // 4 KB overlay (argmax)
    int*   sOff  = (int*)(smem + 16640);              // 128 B
    float (*sqred)[8] = (float(*)[8])(smem + 16768);  // 1 KB

    int bh = blockIdx.x;                // b*32 + h1
    int cs = blockIdx.y;                // 0..11, 64 channels each
    int b = bh >> 5, h1 = bh & 31;
    int n0 = b * 1024 + h1 * 32;
    int tid = threadIdx.x;

    // ---- embedded argmax (R5 k_argmax summation order, bit-identical) ----
    {
        int k8 = tid >> 5, nl = tid & 31;
        #pragma unroll
        for (int kk = 0; kk < 2; ++kk) {
            int k = k8 + kk * 8;
            double s = 0.0;
            #pragma unroll
            for (int c = 0; c < NSPLIT; ++c)
                s += d2p[((size_t)c * 16 + k) * NP + n0 + nl];
            s2[k][nl] = s;
        }
        __syncthreads();
        if (tid < 32) {
            double best = s2[0][tid]; int bi = 0;
            #pragma unroll
            for (int k = 1; k < 16; ++k) {
                double v = s2[k][tid];
                if (v > best) { best = v; bi = k; }
            }
            sOff[tid] = (bi >> 2) * 128 + 4 * tid + (bi & 3);
        }
        __syncthreads();
    }

    // ---- gather + pack + b2 (R2/R5-proven; ytile overwrites dead s2) ----
    int c_loc = tid & 7, n_loc = tid >> 3;
    int ch_s = tid >> 5, part = tid & 31;
    int off = sOff[n_loc];
    int n = n0 + n_loc;
    float sq = 0.f;
    for (int kt = 0; kt < 8; ++kt) {
        int c0 = cs * 64 + kt * 8;
        __syncthreads();
        const float* src = y + ((size_t)(b * 768 + c0 + ch_s) * 128 + 4 * h1) * 128;
        #pragma unroll
        for (int u = 0; u < 4; ++u)
            *(float4*)&ytile[ch_s][u * 128 + part * 4] = *(const float4*)(src + u * 128 + part * 4);
        __syncthreads();
        float v = ytile[c_loc][off];
        size_t o = (size_t)n * CD + c0 + c_loc;
        Yhi[o] = f2bf(v);
        sq += v * v;
    }
    sqred[n_loc][c_loc] = sq;
    __syncthreads();
    if (tid < 32) {
        float s = 0.f;
        #pragma unroll
        for (int g = 0; g < 8; ++g) s += sqred[tid][g];
        atomicAdd(&b2f[n0 + tid], s);
    }
}

// ---------------------------------------------------------------------------
// MFMA Gram + exp-sum, 1-term (Gram = a_hi . b_hi), K=768 as 12 windows of
// K=64; XOR-(r&7) swizzle on 64-short rows; bijective XCD block swizzle.
__global__ __launch_bounds__(256, 3)
void k_mmd_mfma(const unsigned short* __restrict__ Xhi,
                const unsigned short* __restrict__ Yhi,
                const float* __restrict__ a2, const float* __restrict__ b2,
                double* __restrict__ accg, unsigned int* __restrict__ done,
                float* __restrict__ out) {
    __shared__ unsigned short As[128 * 64];   // 16 KB
    __shared__ unsigned short Bs[128 * 64];   // 16 KB
    __shared__ float red[256];

    int bid0 = blockIdx.x;
    int id = (bid0 & 7) * 66 + (bid0 >> 3);   // XCD swizzle, bijective (528=8*66)
    int z, bx, by;
    double w = 1.0;
    if (id < 272) {
        z = (id < 136) ? 0 : 1;
        if (id >= 136) id -= 136;
        int r = 0;
        while (id >= 16 - r) { id -= 16 - r; ++r; }
        by = r; bx = r + id;
        if (bx != by) w = 2.0;
    } else {
        z = 2; id -= 272;
        bx = id & 15; by = id >> 4;
    }
    const unsigned short* AH = (z == 1) ? Yhi : Xhi;
    const unsigned short* BH = (z == 0) ? Xhi : Yhi;
    const float* na = (z == 1) ? b2 : a2;
    const float* nb = (z == 0) ? a2 : b2;
    int i0 = by * 128, j0 = bx * 128;

    int tid = threadIdx.x;
    int lane = tid & 63;
    int wv = tid >> 6;
    int wr = wv >> 1, wc = wv & 1;
    int m = lane & 15, q = lane >> 4;
    int lrow = lane >> 3, lchunk = lane & 7;   // staging: 8 rows x 8 chunks/wave

    f32x4 acc[4][4] = {};

    for (int wnd = 0; wnd < 12; ++wnd) {
        int c0 = wnd * 64;
        __syncthreads();
        #pragma unroll
        for (int s = 0; s < 4; ++s) {
            int r0 = s * 32 + wv * 8;
            int r  = r0 + lrow;
            int cg = lchunk ^ (r & 7);
            GLD16(AH + (size_t)(i0 + r) * CD + c0 + cg * 8, &As[r0 * 64]);
        }
        #pragma unroll
        for (int s = 0; s < 4; ++s) {
            int r0 = s * 32 + wv * 8;
            int r  = r0 + lrow;
            int cg = lchunk ^ (r & 7);
            GLD16(BH + (size_t)(j0 + r) * CD + c0 + cg * 8, &Bs[r0 * 64]);
        }
        __syncthreads();
        #pragma unroll
        for (int kh = 0; kh < 2; ++kh) {      // two K=32 halves of the window
            bf16frag af[4], bg[4];
            #pragma unroll
            for (int t = 0; t < 4; ++t) {
                int ra = wr * 64 + t * 16 + m;
                af[t] = *(const bf16frag*)&As[ra * 64 + ((kh * 4 + q) ^ (ra & 7)) * 8];
            }
            #pragma unroll
            for (int t = 0; t < 4; ++t) {
                int rb = wc * 64 + t * 16 + m;
                bg[t] = *(const bf16frag*)&Bs[rb * 64 + ((kh * 4 + q) ^ (rb & 7)) * 8];
            }
            #pragma unroll
            for (int ti = 0; ti < 4; ++ti)
                #pragma unroll
                for (int tj = 0; tj < 4; ++tj)
                    acc[ti][tj] = __builtin_amdgcn_mfma_f32_16x16x32_bf16(
                        af[ti], bg[tj], acc[ti][tj], 0, 0, 0);
        }
    }

    float s = 0.0f;
    #pragma unroll
    for (int ti = 0; ti < 4; ++ti) {
        #pragma unroll
        for (int r = 0; r < 4; ++r) {
            int i = i0 + wr * 64 + ti * 16 + q * 4 + r;
            float ai = na[i];
            #pragma unroll
            for (int tj = 0; tj < 4; ++tj) {
                int j = j0 + wc * 64 + tj * 16 + m;
                float d = ai + nb[j] - 2.0f * acc[ti][tj][r];
                d = fmaxf(d, 0.0f);
                s += expf(-MMD_GAMMA * d);
            }
        }
    }
    red[tid] = s;
    __syncthreads();
    for (int st = 128; st > 0; st >>= 1) {
        if (tid < st) red[tid] += red[tid + st];
        __syncthreads();
    }
    if (tid == 0) {
        atomicAdd(&accg[z], w * (double)red[0]);
        __threadfence();                           // accg visible before done++
        unsigned int d = atomicAdd(done, 1u);
        if (d == (unsigned int)(NJOBS - 1)) {      // last block finalizes
            double kxx = atomicAdd(&accg[0], 0.0); // atomic-RMW read: coherent
            double kyy = atomicAdd(&accg[1], 0.0);
            double kxy = atomicAdd(&accg[2], 0.0);
            const double inv = 1.0 / ((double)NP * (double)NP);
            out[0] = (float)((kxx + kyy - 2.0 * kxy) * inv);
        }
    }
}

extern "C" void kernel_launch(void* const* d_in, const int* in_sizes, int n_in,
                              void* d_out, int out_size, void* d_ws, size_t ws_size,
                              hipStream_t stream) {
    const float* x = (const float*)d_in[0];
    const float* y = (const float*)d_in[1];
    float* out = (float*)d_out;

    char* ws = (char*)d_ws;
    double*       acc  = (double*)ws;                 // [0,24)
    unsigned int* done = (unsigned int*)(ws + 64);    // 4B
    float*  b2f  = (float*)(ws + 4096);               // 8KB
    float*  a2f  = (float*)(ws + 12288);              // 8KB
    double* d2p  = (double*)(ws + 32768);             // 6.29MB -> ends 6324224
    unsigned short* Xhi = (unsigned short*)(ws + 6324224);   // 3.0MB
    unsigned short* Yhi = (unsigned short*)(ws + 9469952);   // 3.0MB

    hipMemsetAsync(ws, 0, 20480, stream);             // acc + done + b2f + a2f
    k_prep<<<2304, 256, 0, stream>>>(x, y, d2p, Xhi, a2f);
    k_gather_pack_y<<<dim3(64, 12), 256, 0, stream>>>(y, d2p, Yhi, b2f);
    k_mmd_mfma<<<NJOBS, 256, 0, stream>>>(Xhi, Yhi, a2f, b2f, acc, done, out);
}

// Round 10
// 207.654 us; speedup vs baseline: 2.1680x; 1.0775x over previous
//
#include <hip/hip_runtime.h>

// Problem constants
#define NP 2048          // B*H1*W1 points
#define CD 768           // channels
#define NSPLIT 24        // channel splits for d2 partials (32 ch each)
#define NJOBS 528        // 136 XX-tri + 136 YY-tri + 256 XY tiles
#define MMD_GAMMA 0.00065f

typedef short bf16frag __attribute__((ext_vector_type(8)));
typedef float f32x4 __attribute__((ext_vector_type(4)));
typedef unsigned short u16x4 __attribute__((ext_vector_type(4)));
typedef unsigned short u16x8 __attribute__((ext_vector_type(8)));

#define GLD16(g, l)  __builtin_amdgcn_global_load_lds(                      \
    (const __attribute__((address_space(1))) void*)(g),                     \
    (__attribute__((address_space(3))) void*)(l), 16, 0, 0)

static __device__ inline unsigned short f2bf(float v) {
    union { float f; unsigned u; } a; a.f = v;
    unsigned r = a.u + 0x7fffu + ((a.u >> 16) & 1u);
    return (unsigned short)(r >> 16);
}

#define CT_PITCH 520     // u16 pitch per channel row (512 + 8 pad)

// ---------------------------------------------------------------------------
// Fused prep (R4 VERBATIM — measured 64us, absmax 0.0):
//   blocks 0..1535  = d2 partials + bf16 candidate store + y^2 partials.
//     block = (cs 0..23, b, h1): contiguous 2KB y channel-rows. Thread
//     (cg,w1) owns all 16 (i,j) candidates; per-candidate f64 channel order
//     ascending. Candidates packed to bf16 via LDS -> Ycand[n*16+cand][c].
//   blocks 1536..2303 = x transpose + bf16 pack + a2 partials.
__global__ __launch_bounds__(256, 4)
void k_prep(const float* __restrict__ x, const float* __restrict__ y,
            double* __restrict__ d2p,
            unsigned short* __restrict__ Xhi,
            float* __restrict__ a2f,
            unsigned short* __restrict__ Ycand,
            float* __restrict__ b2cand) {
    // 33.3 KB union: ct[32][CT_PITCH] u16; redd/sqrd2 overlay ct after readout
    __shared__ __attribute__((aligned(16))) unsigned char smem[32 * CT_PITCH * 2];
    unsigned short* ctU   = (unsigned short*)smem;
    double*         redd  = (double*)smem;                    // 8 KB overlay
    float*          sqrd2 = (float*)(smem + 8192);            // 4 KB overlay
    float*          tile  = (float*)smem;                     // 8.4 KB (transpose)
    float*          sqred = (float*)(smem + 8448);            // 1 KB (transpose)

    int bid = blockIdx.x;
    int tid = threadIdx.x;

    if (bid < 1536) {
        // ---- d2 partial branch + candidate pack ----
        int cs = bid >> 6;               // 0..23 (32 channels each)
        int r6 = bid & 63;
        int b = r6 >> 5, h1 = r6 & 31;
        int cg = tid >> 5, w1 = tid & 31;
        int cbase = cs * 32;

        double acc[4][4] = {};
        float  q[4][4] = {};

        #pragma unroll
        for (int kk = 0; kk < 4; ++kk) {
            int c = cbase + 8 * kk + cg;             // ascending per thread
            const float* yrow =
                y + ((size_t)(b * 768 + c) * 128 + 4 * h1) * 128 + 4 * w1;
            float4 yv0 = *(const float4*)(yrow);
            float4 yv1 = *(const float4*)(yrow + 128);
            float4 yv2 = *(const float4*)(yrow + 256);
            float4 yv3 = *(const float4*)(yrow + 384);
            float xv = x[(size_t)(b * 768 + c) * 1024 + h1 * 32 + w1];
            // pack 16 candidates (i,j) of this channel -> LDS row slice
            int cl = 8 * kk + cg;
            u16x8 pk0 = { f2bf(yv0.x), f2bf(yv0.y), f2bf(yv0.z), f2bf(yv0.w),
                          f2bf(yv1.x), f2bf(yv1.y), f2bf(yv1.z), f2bf(yv1.w) };
            u16x8 pk1 = { f2bf(yv2.x), f2bf(yv2.y), f2bf(yv2.z), f2bf(yv2.w),
                          f2bf(yv3.x), f2bf(yv3.y), f2bf(yv3.z), f2bf(yv3.w) };
            *(u16x8*)&ctU[cl * CT_PITCH + w1 * 16]     = pk0;
            *(u16x8*)&ctU[cl * CT_PITCH + w1 * 16 + 8] = pk1;
            // y^2 partials (f32)
            q[0][0] += yv0.x * yv0.x; q[0][1] += yv0.y * yv0.y;
            q[0][2] += yv0.z * yv0.z; q[0][3] += yv0.w * yv0.w;
            q[1][0] += yv1.x * yv1.x; q[1][1] += yv1.y * yv1.y;
            q[1][2] += yv1.z * yv1.z; q[1][3] += yv1.w * yv1.w;
            q[2][0] += yv2.x * yv2.x; q[2][1] += yv2.y * yv2.y;
            q[2][2] += yv2.z * yv2.z; q[2][3] += yv2.w * yv2.w;
            q[3][0] += yv3.x * yv3.x; q[3][1] += yv3.y * yv3.y;
            q[3][2] += yv3.z * yv3.z; q[3][3] += yv3.w * yv3.w;
            // d2 partials (f64), per-candidate ascending-channel order
            double xd = (double)xv;
            {
                double d;
                d = xd - (double)yv0.x; acc[0][0] += d * d;
                d = xd - (double)yv0.y; acc[0][1] += d * d;
                d = xd - (double)yv0.z; acc[0][2] += d * d;
                d = xd - (double)yv0.w; acc[0][3] += d * d;
                d = xd - (double)yv1.x; acc[1][0] += d * d;
                d = xd - (double)yv1.y; acc[1][1] += d * d;
                d = xd - (double)yv1.z; acc[1][2] += d * d;
                d = xd - (double)yv1.w; acc[1][3] += d * d;
                d = xd - (double)yv2.x; acc[2][0] += d * d;
                d = xd - (double)yv2.y; acc[2][1] += d * d;
                d = xd - (double)yv2.z; acc[2][2] += d * d;
                d = xd - (double)yv2.w; acc[2][3] += d * d;
                d = xd - (double)yv3.x; acc[3][0] += d * d;
                d = xd - (double)yv3.y; acc[3][1] += d * d;
                d = xd - (double)yv3.z; acc[3][2] += d * d;
                d = xd - (double)yv3.w; acc[3][3] += d * d;
            }
        }
        __syncthreads();
        // ---- candidate readout: 512 rows x 32 ch; 64B/row, full-line writes
        int n0 = b * 1024 + h1 * 32;
        #pragma unroll
        for (int rr = 0; rr < 2; ++rr) {
            int r = tid + rr * 256;                  // 0..511
            int w1r = r >> 4, ii = (r >> 2) & 3, jj = r & 3;
            size_t rowbase = ((size_t)(n0 + w1r) * 16 + ii * 4 + jj) * CD + cbase;
            #pragma unroll
            for (int u4 = 0; u4 < 4; ++u4) {
                u16x8 v;
                #pragma unroll
                for (int u = 0; u < 8; ++u) {
                    int cl = u4 * 8 + u;
                    v[u] = ctU[cl * CT_PITCH + w1r * 16 + ii * 4 + jj];
                }
                *(u16x8*)&Ycand[rowbase + u4 * 8] = v;
            }
        }
        // ---- reduce rounds (redd/sqrd2 overlay the now-dead ct region) ----
        #pragma unroll 1
        for (int i = 0; i < 4; ++i) {
            __syncthreads();                         // guards overlay / prev round
            int base = (cg * 32 + w1) * 4;
            redd[base + 0] = acc[i][0]; redd[base + 1] = acc[i][1];
            redd[base + 2] = acc[i][2]; redd[base + 3] = acc[i][3];
            sqrd2[base + 0] = q[i][0]; sqrd2[base + 1] = q[i][1];
            sqrd2[base + 2] = q[i][2]; sqrd2[base + 3] = q[i][3];
            __syncthreads();
            if (tid < 128) {
                int w = tid & 31, jj = tid >> 5;
                double s = 0.0;
                #pragma unroll
                for (int g = 0; g < 8; ++g) s += redd[(g * 32 + w) * 4 + jj];
                d2p[((size_t)(cs * 16) + i * 4 + jj) * NP + n0 + w] = s;
            } else {
                int t2 = tid - 128;
                int w = t2 & 31, jj = t2 >> 5;
                float s = 0.f;
                #pragma unroll
                for (int g = 0; g < 8; ++g) s += sqrd2[(g * 32 + w) * 4 + jj];
                atomicAdd(&b2cand[(size_t)(n0 + w) * 16 + i * 4 + jj], s);
            }
        }
    } else {
        // ---- transpose + pack branch (unchanged) ----
        int id = bid - 1536;
        int bx = id & 63;
        int c0 = (id >> 6) * 64;
        int b = bx >> 5, h1 = bx & 31;
        const float* src = x + (size_t)(b * 768 + c0) * 1024 + h1 * 32;
        #pragma unroll
        for (int p = 0; p < 8; ++p) {
            int cl = p * 8 + (tid >> 5);
            int w1 = tid & 31;
            tile[cl * 33 + w1] = src[(size_t)cl * 1024 + w1];
        }
        __syncthreads();
        int n0 = bx * 32;
        #pragma unroll
        for (int p = 0; p < 8; ++p) {
            int w1 = p * 4 + (tid >> 6);
            int c  = tid & 63;
            float v = tile[c * 33 + w1];
            size_t o = (size_t)(n0 + w1) * CD + c0 + c;
            Xhi[o] = f2bf(v);
        }
        {
            int w1 = tid & 31, cseg = tid >> 5;
            float s = 0.f;
            #pragma unroll
            for (int u = 0; u < 8; ++u) {
                float v = tile[(cseg * 8 + u) * 33 + w1];
                s += v * v;
            }
            sqred[cseg * 32 + w1] = s;
        }
        __syncthreads();
        if (tid < 32) {
            float s = 0.f;
            #pragma unroll
            for (int g = 0; g < 8; ++g) s += sqred[g * 32 + tid];
            atomicAdd(&a2f[n0 + tid], s);
        }
    }
}

// ---------------------------------------------------------------------------
// Merged select: R5's parallel argmax (c-ascending per-candidate sums ->
// bit-identical winners to R4's serial select, proven by R5 passing) + R4's
// row copy. 64 blocks x 256 threads; all d2p reads coalesced.
__global__ __launch_bounds__(256, 4)
void k_select(const double* __restrict__ d2p,
              const unsigned short* __restrict__ Ycand,
              const float* __restrict__ b2cand,
              unsigned short* __restrict__ Yhi,
              float* __restrict__ b2f) {
    __shared__ double s2[16][32];
    __shared__ int sBi[32];
    int bh = blockIdx.x;                 // b*32 + h1
    int b = bh >> 5, h1 = bh & 31;
    int n0 = b * 1024 + h1 * 32;
    int tid = threadIdx.x;
    {
        int k8 = tid >> 5, nl = tid & 31;
        #pragma unroll
        for (int kk = 0; kk < 2; ++kk) {
            int k = k8 + kk * 8;
            double s = 0.0;
            #pragma unroll
            for (int c = 0; c < NSPLIT; ++c)      // c ascending: proven order
                s += d2p[((size_t)c * 16 + k) * NP + n0 + nl];
            s2[k][nl] = s;
        }
    }
    __syncthreads();
    if (tid < 32) {
        double best = s2[0][tid]; int bi = 0;
        #pragma unroll
        for (int k = 1; k < 16; ++k) {
            double v = s2[k][tid];
            if (v > best) { best = v; bi = k; }
        }
        sBi[tid] = bi;
        b2f[n0 + tid] = b2cand[(size_t)(n0 + tid) * 16 + bi];
    }
    __syncthreads();
    int n_loc = tid >> 3, c8 = tid & 7;
    size_t srow = ((size_t)(n0 + n_loc) * 16 + sBi[n_loc]) * CD;
    size_t drow = (size_t)(n0 + n_loc) * CD;
    #pragma unroll
    for (int it = 0; it < 12; ++it) {
        size_t o = (size_t)it * 64 + c8 * 8;
        *(u16x8*)&Yhi[drow + o] = *(const u16x8*)&Ycand[srow + o];
    }
}

// ---------------------------------------------------------------------------
// MFMA Gram + exp-sum, 1-term (Gram = a_hi . b_hi), K=768 as 12 windows of
// K=64; XOR-(r&7) swizzle on 64-short rows; bijective XCD block swizzle.
__global__ __launch_bounds__(256, 3)
void k_mmd_mfma(const unsigned short* __restrict__ Xhi,
                const unsigned short* __restrict__ Yhi,
                const float* __restrict__ a2, const float* __restrict__ b2,
                double* __restrict__ accg, unsigned int* __restrict__ done,
                float* __restrict__ out) {
    __shared__ unsigned short As[128 * 64];   // 16 KB
    __shared__ unsigned short Bs[128 * 64];   // 16 KB
    __shared__ float red[256];

    int bid0 = blockIdx.x;
    int id = (bid0 & 7) * 66 + (bid0 >> 3);   // XCD swizzle, bijective (528=8*66)
    int z, bx, by;
    double w = 1.0;
    if (id < 272) {
        z = (id < 136) ? 0 : 1;
        if (id >= 136) id -= 136;
        int r = 0;
        while (id >= 16 - r) { id -= 16 - r; ++r; }
        by = r; bx = r + id;
        if (bx != by) w = 2.0;
    } else {
        z = 2; id -= 272;
        bx = id & 15; by = id >> 4;
    }
    const unsigned short* AH = (z == 1) ? Yhi : Xhi;
    const unsigned short* BH = (z == 0) ? Xhi : Yhi;
    const float* na = (z == 1) ? b2 : a2;
    const float* nb = (z == 0) ? a2 : b2;
    int i0 = by * 128, j0 = bx * 128;

    int tid = threadIdx.x;
    int lane = tid & 63;
    int wv = tid >> 6;
    int wr = wv >> 1, wc = wv & 1;
    int m = lane & 15, q = lane >> 4;
    int lrow = lane >> 3, lchunk = lane & 7;   // staging: 8 rows x 8 chunks/wave

    f32x4 acc[4][4] = {};

    for (int wnd = 0; wnd < 12; ++wnd) {
        int c0 = wnd * 64;
        __syncthreads();
        #pragma unroll
        for (int s = 0; s < 4; ++s) {
            int r0 = s * 32 + wv * 8;
            int r  = r0 + lrow;
            int cg = lchunk ^ (r & 7);
            GLD16(AH + (size_t)(i0 + r) * CD + c0 + cg * 8, &As[r0 * 64]);
        }
        #pragma unroll
        for (int s = 0; s < 4; ++s) {
            int r0 = s * 32 + wv * 8;
            int r  = r0 + lrow;
            int cg = lchunk ^ (r & 7);
            GLD16(BH + (size_t)(j0 + r) * CD + c0 + cg * 8, &Bs[r0 * 64]);
        }
        __syncthreads();
        #pragma unroll
        for (int kh = 0; kh < 2; ++kh) {      // two K=32 halves of the window
            bf16frag af[4], bg[4];
            #pragma unroll
            for (int t = 0; t < 4; ++t) {
                int ra = wr * 64 + t * 16 + m;
                af[t] = *(const bf16frag*)&As[ra * 64 + ((kh * 4 + q) ^ (ra & 7)) * 8];
            }
            #pragma unroll
            for (int t = 0; t < 4; ++t) {
                int rb = wc * 64 + t * 16 + m;
                bg[t] = *(const bf16frag*)&Bs[rb * 64 + ((kh * 4 + q) ^ (rb & 7)) * 8];
            }
            #pragma unroll
            for (int ti = 0; ti < 4; ++ti)
                #pragma unroll
                for (int tj = 0; tj < 4; ++tj)
                    acc[ti][tj] = __builtin_amdgcn_mfma_f32_16x16x32_bf16(
                        af[ti], bg[tj], acc[ti][tj], 0, 0, 0);
        }
    }

    float s = 0.0f;
    #pragma unroll
    for (int ti = 0; ti < 4; ++ti) {
        #pragma unroll
        for (int r = 0; r < 4; ++r) {
            int i = i0 + wr * 64 + ti * 16 + q * 4 + r;
            float ai = na[i];
            #pragma unroll
            for (int tj = 0; tj < 4; ++tj) {
                int j = j0 + wc * 64 + tj * 16 + m;
                float d = ai + nb[j] - 2.0f * acc[ti][tj][r];
                d = fmaxf(d, 0.0f);
                s += expf(-MMD_GAMMA * d);
            }
        }
    }
    red[tid] = s;
    __syncthreads();
    for (int st = 128; st > 0; st >>= 1) {
        if (tid < st) red[tid] += red[tid + st];
        __syncthreads();
    }
    if (tid == 0) {
        atomicAdd(&accg[z], w * (double)red[0]);
        __threadfence();                           // accg visible before done++
        unsigned int d = atomicAdd(done, 1u);
        if (d == (unsigned int)(NJOBS - 1)) {      // last block finalizes
            double kxx = atomicAdd(&accg[0], 0.0); // atomic-RMW read: coherent
            double kyy = atomicAdd(&accg[1], 0.0);
            double kxy = atomicAdd(&accg[2], 0.0);
            const double inv = 1.0 / ((double)NP * (double)NP);
            out[0] = (float)((kxx + kyy - 2.0 * kxy) * inv);
        }
    }
}

extern "C" void kernel_launch(void* const* d_in, const int* in_sizes, int n_in,
                              void* d_out, int out_size, void* d_ws, size_t ws_size,
                              hipStream_t stream) {
    const float* x = (const float*)d_in[0];
    const float* y = (const float*)d_in[1];
    float* out = (float*)d_out;

    char* ws = (char*)d_ws;
    double*       acc    = (double*)ws;                  // [0,24)
    unsigned int* done   = (unsigned int*)(ws + 64);     // 4B
    float*  b2f    = (float*)(ws + 4096);                // 8KB
    float*  a2f    = (float*)(ws + 12288);               // 8KB
    float*  b2cand = (float*)(ws + 20480);               // 128KB -> ends 151552
    double* d2p    = (double*)(ws + 151552);             // 6.29MB -> ends 6443008
    unsigned short* Xhi   = (unsigned short*)(ws + 6443008);    // 3.0MB
    unsigned short* Yhi   = (unsigned short*)(ws + 9588736);    // 3.0MB
    unsigned short* Ycand = (unsigned short*)(ws + 12734464);   // 48MB

    hipMemsetAsync(ws, 0, 151552, stream);   // acc + done + b2f + a2f + b2cand
    k_prep<<<2304, 256, 0, stream>>>(x, y, d2p, Xhi, a2f, Ycand, b2cand);
    k_select<<<64, 256, 0, stream>>>(d2p, Ycand, b2cand, Yhi, b2f);
    k_mmd_mfma<<<NJOBS, 256, 0, stream>>>(Xhi, Yhi, a2f, b2f, acc, done, out);
}